// Round 5
// baseline (403.606 us; speedup 1.0000x reference)
//
#include <hip/hip_runtime.h>

#define GROUPS 32
#define CPG    16
#define C_DIM  512
#define HW     1024
#define B_DIM  32

typedef __attribute__((ext_vector_type(8))) short bf16x8;
typedef __attribute__((ext_vector_type(4))) float f32x4;
typedef __attribute__((ext_vector_type(8))) unsigned short u16x8;

__device__ inline unsigned short f2bf(float f) {
  unsigned u = __builtin_bit_cast(unsigned, f);
  u += 0x7fff + ((u >> 16) & 1);   // RNE
  return (unsigned short)(u >> 16);
}
__device__ inline float bf2f(unsigned short s) {
  return __builtin_bit_cast(float, ((unsigned)s) << 16);
}

__device__ inline void mfma16(f32x4& d, bf16x8 a, bf16x8 b) {
  asm("v_mfma_f32_16x16x32_bf16 %0, %1, %2, %0" : "+v"(d) : "v"(a), "v"(b));
}

// ---- 256x256x64 core, 8 waves (2M strip-interleaved x 4N), dbuf LDS 128KB ----
// LDS linear [row][64] rows of 128B. T2 swizzle via PRE-SWIZZLED GLOBAL SOURCE
// (chunk^=row&7 within each 128B row; same line -> coalescing intact) + same
// XOR on ds_read chunk index => 2-way banks (free). global_load_lds dest is
// wave-uniform base; lane*16B gives row=base+lane>>3, slot=lane&7.
__device__ __forceinline__ void stage_h(const unsigned short* g0, size_t stride,
                                        unsigned short* ldsbase, int half, int w, int lane) {
#pragma unroll
  for (int i = 0; i < 2; ++i) {
    int rbase = half * 128 + w * 16 + i * 8;          // wave-uniform
    int row = rbase + (lane >> 3);
    int chunk = (lane & 7) ^ (lane >> 3);             // == (lane&7) ^ (row&7)
    const unsigned short* g = g0 + (size_t)row * stride + chunk * 8;
    unsigned short* l = ldsbase + rbase * 64;
    __builtin_amdgcn_global_load_lds((const __attribute__((address_space(1))) void*)g,
                                     (__attribute__((address_space(3))) void*)l, 16, 0, 0);
  }
}

// Counted-vmcnt schedule. Issue order per iter: ph0 stages B0,B1(next); ph1
// stages A0,A1(next). Phase-p MFMAs read A-half-p (strip p rows = p*128+wm*64)
// + all B. In-order load completion => ph0 needs first 6 of tile's 8 loads:
// younger = A1(cur)2 + newB4 = vmcnt(6); ph1 needs A1: younger = 8 = vmcnt(8).
// Tail iter (no issues): vmcnt(2)/vmcnt(0). Raw s_barrier: loads stay in
// flight across barriers (T4). Tile-end barrier protects buffer swap.
__device__ __forceinline__ void gemm256_core(const unsigned short* Ag, size_t sA,
                                             const unsigned short* Bg, size_t sB,
                                             int nkt, unsigned short* lds,
                                             f32x4 (&acc)[2][4][4],
                                             int lane, int w, int wm, int wn) {
  unsigned short* Ab[2] = { lds, lds + 16384 };
  unsigned short* Bb[2] = { lds + 32768, lds + 49152 };
  stage_h(Bg, sB, Bb[0], 0, w, lane);
  stage_h(Bg, sB, Bb[0], 1, w, lane);
  stage_h(Ag, sA, Ab[0], 0, w, lane);
  stage_h(Ag, sA, Ab[0], 1, w, lane);
  int cur = 0;
  for (int t = 0; t < nkt; ++t) {
    const unsigned short* As = Ab[cur];
    const unsigned short* Bs = Bb[cur];
    const unsigned short* An = Ag + (size_t)(t + 1) * 64;
    const unsigned short* Bn = Bg + (size_t)(t + 1) * 64;
    bool last = (t == nkt - 1);
    bf16x8 bfr[4][2];
    // -------- phase 0: strip0 --------
    if (!last) {
      stage_h(Bn, sB, Bb[cur ^ 1], 0, w, lane);
      stage_h(Bn, sB, Bb[cur ^ 1], 1, w, lane);
      asm volatile("s_waitcnt vmcnt(6)" ::: "memory");
    } else {
      asm volatile("s_waitcnt vmcnt(2)" ::: "memory");
    }
    __builtin_amdgcn_s_barrier();
    __builtin_amdgcn_sched_barrier(0);
    {
      int g4 = lane >> 4;
      bf16x8 af[4][2];
#pragma unroll
      for (int ni = 0; ni < 4; ++ni) {
        int r = wn * 64 + ni * 16 + (lane & 15);
#pragma unroll
        for (int kk = 0; kk < 2; ++kk)
          bfr[ni][kk] = *(const bf16x8*)&Bs[r * 64 + (((kk * 4 + g4) ^ (r & 7)) << 3)];
      }
#pragma unroll
      for (int mi = 0; mi < 4; ++mi) {
        int r = wm * 64 + mi * 16 + (lane & 15);
#pragma unroll
        for (int kk = 0; kk < 2; ++kk)
          af[mi][kk] = *(const bf16x8*)&As[r * 64 + (((kk * 4 + g4) ^ (r & 7)) << 3)];
      }
      __builtin_amdgcn_s_setprio(1);
#pragma unroll
      for (int kk = 0; kk < 2; ++kk)
#pragma unroll
        for (int mi = 0; mi < 4; ++mi)
#pragma unroll
          for (int ni = 0; ni < 4; ++ni)
            mfma16(acc[0][mi][ni], af[mi][kk], bfr[ni][kk]);
      __builtin_amdgcn_s_setprio(0);
    }
    // -------- phase 1: strip1 --------
    if (!last) {
      stage_h(An, sA, Ab[cur ^ 1], 0, w, lane);
      stage_h(An, sA, Ab[cur ^ 1], 1, w, lane);
      asm volatile("s_waitcnt vmcnt(8)" ::: "memory");
    } else {
      asm volatile("s_waitcnt vmcnt(0)" ::: "memory");
    }
    __builtin_amdgcn_s_barrier();
    __builtin_amdgcn_sched_barrier(0);
    {
      int g4 = lane >> 4;
      bf16x8 af[4][2];
#pragma unroll
      for (int mi = 0; mi < 4; ++mi) {
        int r = 128 + wm * 64 + mi * 16 + (lane & 15);
#pragma unroll
        for (int kk = 0; kk < 2; ++kk)
          af[mi][kk] = *(const bf16x8*)&As[r * 64 + (((kk * 4 + g4) ^ (r & 7)) << 3)];
      }
      __builtin_amdgcn_s_setprio(1);
#pragma unroll
      for (int kk = 0; kk < 2; ++kk)
#pragma unroll
        for (int mi = 0; mi < 4; ++mi)
#pragma unroll
          for (int ni = 0; ni < 4; ++ni)
            mfma16(acc[1][mi][ni], af[mi][kk], bfr[ni][kk]);
      __builtin_amdgcn_s_setprio(0);
    }
    // -------- tile end: reads done before next iter's issues overwrite ----
    asm volatile("s_waitcnt lgkmcnt(0)" ::: "memory");
    __builtin_amdgcn_sched_barrier(0);
    __builtin_amdgcn_s_barrier();
    __builtin_amdgcn_sched_barrier(0);
    cur ^= 1;
  }
}

// ---------------- kernel 1: GroupNorm stats ----------------
__global__ __launch_bounds__(256) void gn_stats_k(const float* __restrict__ x,
                                                  float* __restrict__ mean,
                                                  float* __restrict__ rstd) {
  int blk = blockIdx.x;  // b*32+g ; group slab is contiguous 16*1024 floats
  const float4* p = (const float4*)(x + (size_t)blk * (CPG * HW));
  float s = 0.f, ss = 0.f;
  for (int i = threadIdx.x; i < CPG * HW / 4; i += 256) {
    float4 v = p[i];
    s  += v.x + v.y + v.z + v.w;
    ss += v.x * v.x + v.y * v.y + v.z * v.z + v.w * v.w;
  }
#pragma unroll
  for (int off = 32; off > 0; off >>= 1) {
    s  += __shfl_xor(s, off);
    ss += __shfl_xor(ss, off);
  }
  __shared__ float sm[8];
  int wave = threadIdx.x >> 6, lane = threadIdx.x & 63;
  if (lane == 0) { sm[wave] = s; sm[wave + 4] = ss; }
  __syncthreads();
  if (threadIdx.x == 0) {
    float S  = sm[0] + sm[1] + sm[2] + sm[3];
    float SS = sm[4] + sm[5] + sm[6] + sm[7];
    float mu  = S * (1.f / (CPG * HW));
    float var = SS * (1.f / (CPG * HW)) - mu * mu;
    mean[blk] = mu;
    rstd[blk] = rsqrtf(var + 1e-5f);
  }
}

// ---------------- kernel 2: weights -> bf16 (attn scale folded into q,k) ----------------
__global__ __launch_bounds__(256) void prep_k(const float* __restrict__ qkv_w,
                                              const float* __restrict__ qkv_b,
                                              const float* __restrict__ proj_w,
                                              unsigned short* __restrict__ wq_bf,
                                              unsigned short* __restrict__ pw_bf,
                                              float* __restrict__ b_s) {
  const float SC = 0.21022410381342863f;  // 512^-0.25
  int t = blockIdx.x * 256 + threadIdx.x;
  for (int i = t; i < 1536 * 512 / 4; i += gridDim.x * 256) {
    float4 w = *(const float4*)&qkv_w[i * 4];
    float sc = (i * 4 < 1024 * 512) ? SC : 1.f;
    ushort4 o;
    o.x = f2bf(w.x * sc); o.y = f2bf(w.y * sc); o.z = f2bf(w.z * sc); o.w = f2bf(w.w * sc);
    *(ushort4*)&wq_bf[i * 4] = o;
  }
  for (int i = t; i < 512 * 512 / 4; i += gridDim.x * 256) {
    float4 w = *(const float4*)&proj_w[i * 4];
    ushort4 o;
    o.x = f2bf(w.x); o.y = f2bf(w.y); o.z = f2bf(w.z); o.w = f2bf(w.w);
    *(ushort4*)&pw_bf[i * 4] = o;
  }
  if (t < 1536) b_s[t] = qkv_b[t] * (t < 1024 ? SC : 1.f);
}

// ---------------- kernel 3: GN-normalize + transpose -> hn_t[b][p][c] bf16 ----------------
__global__ __launch_bounds__(256) void gn_apply_t_k(const float* __restrict__ x,
                                                    const float* __restrict__ gamma,
                                                    const float* __restrict__ beta,
                                                    const float* __restrict__ mean,
                                                    const float* __restrict__ rstd,
                                                    unsigned short* __restrict__ hn_t) {
  __shared__ unsigned short Ls[64 * 68];
  int b = blockIdx.z, p0 = blockIdx.x * 64, c0 = blockIdx.y * 64;
  int tid = threadIdx.x;
  int c_loc = tid >> 4, p4 = (tid & 15) * 4;
#pragma unroll
  for (int cc = 0; cc < 4; ++cc) {
    int c = c_loc + cc * 16;
    int cg = c0 + c;
    float rs = rstd[b * GROUPS + (cg >> 4)];
    float ga = gamma[cg] * rs;
    float be = beta[cg] - mean[b * GROUPS + (cg >> 4)] * ga;
    float4 x4 = *(const float4*)&x[((size_t)b * C_DIM + cg) * HW + p0 + p4];
    ushort4 o;
    o.x = f2bf(x4.x * ga + be); o.y = f2bf(x4.y * ga + be);
    o.z = f2bf(x4.z * ga + be); o.w = f2bf(x4.w * ga + be);
    *(ushort4*)&Ls[c * 68 + p4] = o;
  }
  __syncthreads();
#pragma unroll
  for (int pass = 0; pass < 2; ++pass) {
    int cid = tid + pass * 256;       // 512 chunks: 64 p-rows x 8 c8
    int p = cid >> 3, c8 = cid & 7;
    u16x8 o;
#pragma unroll
    for (int u = 0; u < 8; ++u) o[u] = Ls[(c8 * 8 + u) * 68 + p];
    *(u16x8*)&hn_t[((size_t)b * HW + p0 + p) * C_DIM + c0 + c8 * 8] = o;
  }
}

// ---------------- kernel 4: QKV GEMM (A=wq_bf[o][c], B=hn_t[p][c]) ----------------
__global__ __launch_bounds__(512, 2) void qkv_gemm_k(
    const unsigned short* __restrict__ wq_bf, const unsigned short* __restrict__ hn_t,
    const float* __restrict__ b_s, unsigned short* __restrict__ q_t,
    unsigned short* __restrict__ k_t, unsigned short* __restrict__ vx) {
  extern __shared__ unsigned short lds[];
  constexpr int NX = 6, NXY = 24, CPX = NXY / 8;
  int tgt = (blockIdx.x & 7) * CPX + (blockIdx.x >> 3);   // T1 XCD chunking
  int bx = tgt % NX, by = tgt / NX;
  int b = blockIdx.z;
  int tid = threadIdx.x, lane = tid & 63, w = tid >> 6, wm = w >> 2, wn = w & 3;
  f32x4 acc[2][4][4] = {};
  const unsigned short* Ag = wq_bf + (size_t)(bx * 256) * C_DIM;
  const unsigned short* Bg = hn_t + ((size_t)b * HW + by * 256) * C_DIM;
  gemm256_core(Ag, C_DIM, Bg, C_DIM, C_DIM / 64, lds, acc, lane, w, wm, wn);
#pragma unroll
  for (int s = 0; s < 2; ++s)
#pragma unroll
    for (int mi = 0; mi < 4; ++mi) {
      int o = bx * 256 + s * 128 + wm * 64 + mi * 16 + ((lane >> 4) << 2);
      float4 bv = *(const float4*)&b_s[o];
      float bb[4] = {bv.x, bv.y, bv.z, bv.w};
#pragma unroll
      for (int ni = 0; ni < 4; ++ni) {
        int p = by * 256 + wn * 64 + ni * 16 + (lane & 15);
        if (bx < 2) {
          ushort4 st;
          st.x = f2bf(acc[s][mi][ni][0] + bb[0]); st.y = f2bf(acc[s][mi][ni][1] + bb[1]);
          st.z = f2bf(acc[s][mi][ni][2] + bb[2]); st.w = f2bf(acc[s][mi][ni][3] + bb[3]);
          *(ushort4*)&q_t[((size_t)b * HW + p) * C_DIM + o] = st;
        } else if (bx < 4) {
          ushort4 st;
          st.x = f2bf(acc[s][mi][ni][0] + bb[0]); st.y = f2bf(acc[s][mi][ni][1] + bb[1]);
          st.z = f2bf(acc[s][mi][ni][2] + bb[2]); st.w = f2bf(acc[s][mi][ni][3] + bb[3]);
          *(ushort4*)&k_t[((size_t)b * HW + p) * C_DIM + (o - 512)] = st;
        } else {
#pragma unroll
          for (int r = 0; r < 4; ++r)
            vx[((size_t)b * C_DIM + (o - 1024) + r) * HW + p] = f2bf(acc[s][mi][ni][r] + bb[r]);
        }
      }
    }
}

// ---------------- kernel 5: S = q k^T (A=q_t[i][c], B=k_t[j][c]) ----------------
__global__ __launch_bounds__(512, 2) void qk_gemm_k(const unsigned short* __restrict__ q_t,
                                                    const unsigned short* __restrict__ k_t,
                                                    unsigned short* __restrict__ S) {
  extern __shared__ unsigned short lds[];
  constexpr int NX = 4, NXY = 16, CPX = NXY / 8;
  int tgt = (blockIdx.x & 7) * CPX + (blockIdx.x >> 3);
  int bx = tgt % NX, by = tgt / NX;
  int b = blockIdx.z;
  int tid = threadIdx.x, lane = tid & 63, w = tid >> 6, wm = w >> 2, wn = w & 3;
  f32x4 acc[2][4][4] = {};
  const unsigned short* Ag = q_t + ((size_t)b * HW + bx * 256) * C_DIM;
  const unsigned short* Bg = k_t + ((size_t)b * HW + by * 256) * C_DIM;
  gemm256_core(Ag, C_DIM, Bg, C_DIM, C_DIM / 64, lds, acc, lane, w, wm, wn);
  unsigned short* Sb = S + (size_t)b * HW * HW;
#pragma unroll
  for (int s = 0; s < 2; ++s)
#pragma unroll
    for (int mi = 0; mi < 4; ++mi) {
      int i0 = bx * 256 + s * 128 + wm * 64 + mi * 16 + ((lane >> 4) << 2);
#pragma unroll
      for (int ni = 0; ni < 4; ++ni) {
        int j = by * 256 + wn * 64 + ni * 16 + (lane & 15);
#pragma unroll
        for (int r = 0; r < 4; ++r)
          Sb[(size_t)(i0 + r) * HW + j] = f2bf(acc[s][mi][ni][r]);
      }
    }
}

// ---------------- kernel 6: row softmax, in place ----------------
__global__ __launch_bounds__(256) void softmax_k(unsigned short* __restrict__ S) {
  int row = blockIdx.x * 4 + (threadIdx.x >> 6);
  int lane = threadIdx.x & 63;
  unsigned short* rp = S + (size_t)row * HW + lane * 16;
  u16x8 a = *(const u16x8*)rp;
  u16x8 c = *(const u16x8*)(rp + 8);
  float f[16];
#pragma unroll
  for (int u = 0; u < 8; ++u) { f[u] = bf2f(a[u]); f[u + 8] = bf2f(c[u]); }
  float m = f[0];
#pragma unroll
  for (int u = 1; u < 16; ++u) m = fmaxf(m, f[u]);
#pragma unroll
  for (int off = 32; off > 0; off >>= 1) m = fmaxf(m, __shfl_xor(m, off));
  float s = 0.f;
#pragma unroll
  for (int u = 0; u < 16; ++u) { f[u] = __expf(f[u] - m); s += f[u]; }
#pragma unroll
  for (int off = 32; off > 0; off >>= 1) s += __shfl_xor(s, off);
  float inv = 1.0f / s;
#pragma unroll
  for (int u = 0; u < 8; ++u) { a[u] = f2bf(f[u] * inv); c[u] = f2bf(f[u + 8] * inv); }
  *(u16x8*)rp = a;
  *(u16x8*)(rp + 8) = c;
}

// ---------------- kernel 7: O^T[i][c] = sum_j P[i][j] v[c][j] ----------------
__global__ __launch_bounds__(512, 2) void pv_gemm_k(const unsigned short* __restrict__ P,
                                                    const unsigned short* __restrict__ vx,
                                                    unsigned short* __restrict__ ha_t) {
  extern __shared__ unsigned short lds[];
  constexpr int NX = 4, NXY = 8, CPX = NXY / 8;
  int tgt = (blockIdx.x & 7) * CPX + (blockIdx.x >> 3);
  int bx = tgt % NX, by = tgt / NX;
  int b = blockIdx.z;
  int tid = threadIdx.x, lane = tid & 63, w = tid >> 6, wm = w >> 2, wn = w & 3;
  f32x4 acc[2][4][4] = {};
  const unsigned short* Ag = P + (size_t)b * HW * HW + (size_t)(bx * 256) * HW;
  const unsigned short* Bg = vx + (size_t)b * C_DIM * HW + (size_t)(by * 256) * HW;
  gemm256_core(Ag, HW, Bg, HW, HW / 64, lds, acc, lane, w, wm, wn);
#pragma unroll
  for (int s = 0; s < 2; ++s)
#pragma unroll
    for (int mi = 0; mi < 4; ++mi) {
      int i0 = bx * 256 + s * 128 + wm * 64 + mi * 16 + ((lane >> 4) << 2);
#pragma unroll
      for (int ni = 0; ni < 4; ++ni) {
        int c = by * 256 + wn * 64 + ni * 16 + (lane & 15);
#pragma unroll
        for (int r = 0; r < 4; ++r)
          ha_t[((size_t)b * HW + i0 + r) * C_DIM + c] = f2bf(acc[s][mi][ni][r]);
      }
    }
}

// ---------------- kernel 8: out = x + proj_w @ O + proj_b ----------------
__global__ __launch_bounds__(512, 2) void proj_gemm_k(const float* __restrict__ x,
                                                      const unsigned short* __restrict__ ha_t,
                                                      const unsigned short* __restrict__ pw_bf,
                                                      const float* __restrict__ proj_b,
                                                      float* __restrict__ out) {
  extern __shared__ unsigned short lds[];
  constexpr int NX = 2, NXY = 8, CPX = NXY / 8;
  int tgt = (blockIdx.x & 7) * CPX + (blockIdx.x >> 3);
  int bx = tgt % NX, by = tgt / NX;
  int b = blockIdx.z;
  int tid = threadIdx.x, lane = tid & 63, w = tid >> 6, wm = w >> 2, wn = w & 3;
  f32x4 acc[2][4][4] = {};
  const unsigned short* Ag = pw_bf + (size_t)(bx * 256) * C_DIM;
  const unsigned short* Bg = ha_t + ((size_t)b * HW + by * 256) * C_DIM;
  gemm256_core(Ag, C_DIM, Bg, C_DIM, C_DIM / 64, lds, acc, lane, w, wm, wn);
  const float* xb = x + (size_t)b * C_DIM * HW;
  float* ob = out + (size_t)b * C_DIM * HW;
#pragma unroll
  for (int s = 0; s < 2; ++s)
#pragma unroll
    for (int mi = 0; mi < 4; ++mi) {
      int o = bx * 256 + s * 128 + wm * 64 + mi * 16 + ((lane >> 4) << 2);
      float4 pb4 = *(const float4*)&proj_b[o];
      float pb[4] = {pb4.x, pb4.y, pb4.z, pb4.w};
#pragma unroll
      for (int ni = 0; ni < 4; ++ni) {
        int p = by * 256 + wn * 64 + ni * 16 + (lane & 15);
#pragma unroll
        for (int r = 0; r < 4; ++r) {
          size_t idx = (size_t)(o + r) * HW + p;
          ob[idx] = xb[idx] + acc[s][mi][ni][r] + pb[r];
        }
      }
    }
}

extern "C" void kernel_launch(void* const* d_in, const int* in_sizes, int n_in,
                              void* d_out, int out_size, void* d_ws, size_t ws_size,
                              hipStream_t stream) {
  const float* x      = (const float*)d_in[0];
  const float* gamma  = (const float*)d_in[1];
  const float* beta   = (const float*)d_in[2];
  const float* qkv_w  = (const float*)d_in[3];
  const float* qkv_b  = (const float*)d_in[4];
  const float* proj_w = (const float*)d_in[5];
  const float* proj_b = (const float*)d_in[6];
  float* out = (float*)d_out;

  // ws: header(4MB incl. weights) | v 32MB | ha_t 32MB | X: hn_t(32MB) / S(64MB aliased)
  // hn_t dead before qk_gemm writes S. q_t/k_t live in d_out (dead before proj writes).
  char* ws = (char*)d_ws;
  float* mean = (float*)ws;
  float* rstd = (float*)(ws + 4096);
  float* b_s  = (float*)(ws + 8192);
  unsigned short* pw_bf = (unsigned short*)(ws + 16384);
  unsigned short* wq_bf = (unsigned short*)(ws + 16384 + 512 * 512 * 2);
  unsigned short* vx   = (unsigned short*)(ws + ((size_t)4 << 20));
  unsigned short* ha_t = (unsigned short*)(ws + ((size_t)36 << 20));
  unsigned short* hn_t = (unsigned short*)(ws + ((size_t)68 << 20));
  unsigned short* S    = (unsigned short*)(ws + ((size_t)68 << 20));
  unsigned short* q_t  = (unsigned short*)d_out;
  unsigned short* k_t  = q_t + (size_t)B_DIM * HW * C_DIM;

  const int SH = 131072;  // 128KB dynamic LDS for the dbuf 256^2 core
  hipFuncSetAttribute((const void*)qkv_gemm_k,  hipFuncAttributeMaxDynamicSharedMemorySize, SH);
  hipFuncSetAttribute((const void*)qk_gemm_k,   hipFuncAttributeMaxDynamicSharedMemorySize, SH);
  hipFuncSetAttribute((const void*)pv_gemm_k,   hipFuncAttributeMaxDynamicSharedMemorySize, SH);
  hipFuncSetAttribute((const void*)proj_gemm_k, hipFuncAttributeMaxDynamicSharedMemorySize, SH);

  gn_stats_k<<<dim3(B_DIM * GROUPS), dim3(256), 0, stream>>>(x, mean, rstd);
  prep_k<<<dim3(512), dim3(256), 0, stream>>>(qkv_w, qkv_b, proj_w, wq_bf, pw_bf, b_s);
  gn_apply_t_k<<<dim3(16, 8, B_DIM), dim3(256), 0, stream>>>(x, gamma, beta, mean, rstd, hn_t);
  qkv_gemm_k<<<dim3(24, 1, B_DIM), dim3(512), SH, stream>>>(wq_bf, hn_t, b_s, q_t, k_t, vx);
  qk_gemm_k<<<dim3(16, 1, B_DIM), dim3(512), SH, stream>>>(q_t, k_t, S);
  softmax_k<<<dim3(B_DIM * HW / 4), dim3(256), 0, stream>>>(S);
  pv_gemm_k<<<dim3(8, 1, B_DIM), dim3(512), SH, stream>>>(S, vx, ha_t);
  proj_gemm_k<<<dim3(8, 1, B_DIM), dim3(512), SH, stream>>>(x, ha_t, pw_bf, proj_b, out);
}